// Round 4
// baseline (1135.121 us; speedup 1.0000x reference)
//
#include <hip/hip_runtime.h>

// Problem constants: BOX=256, OS=1 -> S=256, NC=10, B=16, N=262144
#define S_     256
#define NC_    10
#define CHUNK  1024         // points per staging block
#define TS     32           // scatter tile size (32x32 px)
#define NBIN2  64           // 8x8 tiles of 32px per batch
#define CAPR   4608         // record slab per tile (mean 4096, +8 sigma)
#define IW     33           // LDS image width (32+1 for dx/dy=1 spill)
#define IMSZ   (NC_ * IW * IW)   // 10890 floats = 43.6 KB

typedef unsigned int u32;

__device__ __forceinline__ u32 f2bf(float f) {          // f32 -> bf16 (RNE)
    u32 u = __float_as_uint(f);
    return (u + 0x7fffu + ((u >> 16) & 1u)) >> 16;
}
__device__ __forceinline__ float bf2f(u32 h) { return __uint_as_float(h << 16); }

// Record (24 B, 3x uint2): w0 = qx | qy<<16 (tile-local coords, fp 1/2048 px,
// 16-bit fields: 5-bit cell + 11-bit fraction); w1..w5 = 10 bf16 values.
//
// R4 pipeline: memset(cursor) -> k_scatter (64 coarse bins -> 4x longer
// coalesced runs) -> k_fused (LDS-image f32 atomic deposit, no cell sort)
// -> k_border (border combine + overflow cleanup tail).

// ---- K3: in-LDS counting sort per chunk, then coalesced record flush ----
__global__ void __launch_bounds__(256)
k_scatter(const float* __restrict__ points, const float* __restrict__ values,
          u32* __restrict__ cursor, u32* __restrict__ ovfCnt,
          u32* __restrict__ ovfBuf, uint2* __restrict__ recs, int N) {
    __shared__ u32 cnt[NBIN2];          // histogram -> LDS sort cursor
    __shared__ u32 gOff[NBIN2];         // global slab base - excl
    __shared__ unsigned char binId[CHUNK];
    __shared__ u32 lw[6][CHUNK];        // 24 KB sorted record words (SoA)

    const int tid = threadIdx.x;
    const int cpb = N / CHUNK;
    const int b  = blockIdx.x / cpb;
    const int n0 = (blockIdx.x % cpb) * CHUNK;
    const float* pb = points + (size_t)b * 2 * N;
    const float* vb = values + (size_t)b * NC_ * N;
    const int nb = n0 + tid * 4;

    if (tid < NBIN2) cnt[tid] = 0;

    const float4 pxv = *(const float4*)(pb + nb);
    const float4 pyv = *(const float4*)(pb + (size_t)N + nb);
    float4 vv[NC_];
#pragma unroll
    for (int c = 0; c < NC_; ++c)
        vv[c] = *(const float4*)(vb + (size_t)c * N + nb);

    __syncthreads();                     // cnt zeroed

    // phase 1: quantize 4 points, per-block 64-bin histogram
    float px4[4] = {pxv.x, pxv.y, pxv.z, pxv.w};
    float py4[4] = {pyv.x, pyv.y, pyv.z, pyv.w};
    u32 w0[4], binA[4];
#pragma unroll
    for (int k = 0; k < 4; ++k) {
        float px = (px4[k] + 0.5f) * (float)S_;
        float py = (py4[k] + 0.5f) * (float)S_;
        int xi = (int)floorf(px), yi = (int)floorf(py);
        u32 qx = __float2uint_rn((px - (float)(xi & ~31)) * 2048.0f);
        u32 qy = __float2uint_rn((py - (float)(yi & ~31)) * 2048.0f);
        qx = min(qx, 65535u); qy = min(qy, 65535u);
        w0[k] = qx | (qy << 16);
        binA[k] = (u32)(((yi >> 5) << 3) + (xi >> 5));
        atomicAdd(&cnt[binA[k]], 1u);
    }
    __syncthreads();

    // phase 2: wave-0 shfl exclusive scan of 64 bins + global slab claim
    if (tid < NBIN2) {
        u32 myCnt = cnt[tid];
        u32 x = myCnt;
#pragma unroll
        for (int off = 1; off < 64; off <<= 1) {
            u32 y = __shfl_up(x, off, 64);
            if (tid >= off) x += y;
        }
        u32 excl = x - myCnt;
        u32 gt = (u32)b * NBIN2 + (u32)tid;
        u32 gbase = 0;
        if (myCnt) gbase = gt * (u32)CAPR + atomicAdd(&cursor[gt], myCnt);
        gOff[tid] = gbase - excl;
        cnt[tid] = excl;                 // becomes LDS sort cursor
    }
    __syncthreads();

    // phase 3: pack records, scatter into LDS in bin order
#pragma unroll
    for (int k = 0; k < 4; ++k) {
        u32 bin = binA[k];
        u32 slot = atomicAdd(&cnt[bin], 1u);
        binId[slot] = (unsigned char)bin;
#define VG(c) ((&vv[c].x)[k])
        lw[0][slot] = w0[k];
        lw[1][slot] = f2bf(VG(0)) | (f2bf(VG(1)) << 16);
        lw[2][slot] = f2bf(VG(2)) | (f2bf(VG(3)) << 16);
        lw[3][slot] = f2bf(VG(4)) | (f2bf(VG(5)) << 16);
        lw[4][slot] = f2bf(VG(6)) | (f2bf(VG(7)) << 16);
        lw[5][slot] = f2bf(VG(8)) | (f2bf(VG(9)) << 16);
#undef VG
    }
    __syncthreads();

    // phase 4: coalesced flush; runs now avg 16 records (384 B contiguous)
    const u32 tb0 = (u32)b * NBIN2;
#pragma unroll
    for (int k = 0; k < 4; ++k) {
        u32 r = (u32)tid + (u32)k * 256;
        u32 bin = binId[r];
        u32 dst = gOff[bin] + r;
        u32 a0 = lw[0][r], a1 = lw[1][r], a2 = lw[2][r],
            a3 = lw[3][r], a4 = lw[4][r], a5 = lw[5][r];
        u32 rel = dst - (tb0 + bin) * (u32)CAPR;
        if (rel < (u32)CAPR) {           // always true unless tile > CAPR recs
            size_t s3 = (size_t)dst * 3;
            recs[s3]     = make_uint2(a0, a1);
            recs[s3 + 1] = make_uint2(a2, a3);
            recs[s3 + 2] = make_uint2(a4, a5);
        } else {                         // slab overflow -> side list
            u32 oi = atomicAdd(ovfCnt, 1u);
            u32* ob = ovfBuf + (size_t)oi * 7;
            ob[0] = tb0 + bin;
            ob[1] = a0; ob[2] = a1; ob[3] = a2;
            ob[4] = a3; ob[5] = a4; ob[6] = a5;
        }
    }
}

// ---- K4: LDS-image deposit, one block per 32x32 tile ----
// Streams the tile's records and accumulates into a 33x33x10 f32 LDS image
// with ds_add_f32 (channel offsets are compile-time immediates). Interior
// 31x31 pixels -> plain global stores; 33x33 border ring -> borderBuf.
__global__ void __launch_bounds__(256)
k_fused(const uint2* __restrict__ recs, const u32* __restrict__ cursor,
        float* __restrict__ out, float* __restrict__ borderBuf) {
    __shared__ float img[IMSZ];         // 43.6 KB -> 3 blocks/CU

    const int tid = threadIdx.x;
    const int g = blockIdx.x;                       // batch*64 + tile
    const int batch = g >> 6, t = g & 63;
    const int ox = (t & 7) * TS, oy = (t >> 3) * TS;
    const u32 base = (u32)g * (u32)CAPR;            // fixed slab base
    const u32 n = min(cursor[g], (u32)CAPR);        // overflow -> k_border tail

    for (int p = tid; p < IMSZ; p += 256) img[p] = 0.0f;
    __syncthreads();

    for (u32 i = tid; i < n; i += 256) {
        size_t sa = (size_t)(base + i) * 3;
        uint2 a = recs[sa], b2 = recs[sa + 1], c2 = recs[sa + 2];
        u32 qx = a.x & 0xffffu, qy = a.x >> 16;
        int xi = (int)(qx >> 11), yi = (int)(qy >> 11);
        float rx = (float)(qx & 2047u) * (1.0f / 2048.0f);
        float ry = (float)(qy & 2047u) * (1.0f / 2048.0f);
        float w00 = (1.0f - rx) * (1.0f - ry);      // pixel (xi,   yi  )
        float w10 = rx * (1.0f - ry);               // pixel (xi+1, yi  )
        float w01 = (1.0f - rx) * ry;               // pixel (xi,   yi+1)
        float w11 = rx * ry;                        // pixel (xi+1, yi+1)
        int p00 = yi * IW + xi;
        float v[NC_];
        v[0] = bf2f(a.y & 0xffffu);  v[1] = bf2f(a.y >> 16);
        v[2] = bf2f(b2.x & 0xffffu); v[3] = bf2f(b2.x >> 16);
        v[4] = bf2f(b2.y & 0xffffu); v[5] = bf2f(b2.y >> 16);
        v[6] = bf2f(c2.x & 0xffffu); v[7] = bf2f(c2.x >> 16);
        v[8] = bf2f(c2.y & 0xffffu); v[9] = bf2f(c2.y >> 16);
#pragma unroll
        for (int c = 0; c < NC_; ++c) {
            float vc = v[c];
            float* ib = img + c * (IW * IW) + p00;  // c*IW*IW*4 = imm offset
            atomicAdd(ib,          w00 * vc);
            atomicAdd(ib + 1,      w10 * vc);
            atomicAdd(ib + IW,     w01 * vc);
            atomicAdd(ib + IW + 1, w11 * vc);
        }
    }
    __syncthreads();

    // writeback: interior (lx,ly in 1..31) owned uniquely by this tile
    for (int p = tid; p < IW * IW; p += 256) {
        int lx = p % IW, ly = p / IW;
        bool interior = (lx >= 1) & (lx <= 31) & (ly >= 1) & (ly <= 31);
        if (interior) {
            int gx = ox + lx, gy = oy + ly;
            float* ob = out + (size_t)batch * NC_ * S_ * S_ + gy * S_ + gx;
#pragma unroll
            for (int q = 0; q < NC_; ++q)
                ob[(size_t)q * S_ * S_] = img[q * (IW * IW) + p];
        } else {
            float* bb = borderBuf + ((size_t)g * (IW * IW) + p) * NC_;
#pragma unroll
            for (int q = 0; q < NC_; ++q) bb[q] = img[q * (IW * IW) + p];
        }
    }
}

// ---- K5: combine border partials; tail blocks process slab-overflow list ----
// Border px per batch: 8 cols x 256 + 8 rows x 248 = 4032.
#define CLEAN_T 4096                                 // 16 tail blocks
__global__ void __launch_bounds__(256)
k_border(const float* __restrict__ borderBuf, float* __restrict__ out,
         const u32* __restrict__ ovfCnt, const u32* __restrict__ ovfBuf,
         int total) {
    int idx = blockIdx.x * 256 + threadIdx.x;
    if (idx >= total) {
        // overflow-cleanup role (no-op unless a tile exceeded CAPR records)
        u32 oc = *ovfCnt;
        for (u32 j = (u32)(idx - total); j < oc; j += CLEAN_T) {
            const u32* ob = ovfBuf + (size_t)j * 7;
            u32 g = ob[0];
            int batch = (int)(g >> 6), t = (int)(g & 63u);
            int ox = (t & 7) * TS, oy = (t >> 3) * TS;
            u32 w0 = ob[1];
            u32 qx = w0 & 0xffffu, qy = w0 >> 16;
            int xi = ox + (int)(qx >> 11), yi = oy + (int)(qy >> 11);
            float rx = (float)(qx & 2047u) * (1.0f / 2048.0f);
            float ry = (float)(qy & 2047u) * (1.0f / 2048.0f);
            float v[NC_];
            v[0] = bf2f(ob[2] & 0xffffu); v[1] = bf2f(ob[2] >> 16);
            v[2] = bf2f(ob[3] & 0xffffu); v[3] = bf2f(ob[3] >> 16);
            v[4] = bf2f(ob[4] & 0xffffu); v[5] = bf2f(ob[4] >> 16);
            v[6] = bf2f(ob[5] & 0xffffu); v[7] = bf2f(ob[5] >> 16);
            v[8] = bf2f(ob[6] & 0xffffu); v[9] = bf2f(ob[6] >> 16);
            float* obase = out + (size_t)batch * NC_ * S_ * S_;
            for (int dx = 0; dx < 2; ++dx) {
                int x_ = xi + dx; if (x_ >= S_) continue;
                float wx = dx ? rx : (1.0f - rx);
                for (int dy = 0; dy < 2; ++dy) {
                    int y_ = yi + dy; if (y_ >= S_) continue;
                    float w = wx * (dy ? ry : (1.0f - ry));
                    for (int cc = 0; cc < NC_; ++cc)
                        atomicAdd(obase + (size_t)cc * S_ * S_ + y_ * S_ + x_,
                                  w * v[cc]);
                }
            }
        }
        return;
    }
    int b = idx / 4032;
    int j = idx - b * 4032;
    int gx, gy;
    if (j < 2048) {                                  // vertical lines gx%32==0
        gx = (j >> 8) << 5;
        gy = j & 255;
    } else {                                         // horizontal, gx%32!=0
        int j2 = j - 2048;
        int row = j2 / 248, col = j2 - row * 248;
        gy = row << 5;
        gx = col + 1 + col / 31;                     // 0..247 -> 1..255 \ {32k}
    }

    int txs[2], lxs[2], nx = 0;
    bool bx = (gx & 31) == 0, by = (gy & 31) == 0;
    if (bx) {
        if (gx > 0) { txs[nx] = (gx >> 5) - 1; lxs[nx] = 32; ++nx; }
        txs[nx] = gx >> 5; lxs[nx] = 0; ++nx;
    } else { txs[0] = gx >> 5; lxs[0] = gx & 31; nx = 1; }
    int tys[2], lys[2], ny = 0;
    if (by) {
        if (gy > 0) { tys[ny] = (gy >> 5) - 1; lys[ny] = 32; ++ny; }
        tys[ny] = gy >> 5; lys[ny] = 0; ++ny;
    } else { tys[0] = gy >> 5; lys[0] = gy & 31; ny = 1; }

    float acc[NC_];
#pragma unroll
    for (int q = 0; q < NC_; ++q) acc[q] = 0.0f;
    for (int jj = 0; jj < ny; ++jj)
        for (int ii = 0; ii < nx; ++ii) {
            int g = (b << 6) + (tys[jj] << 3) + txs[ii];
            int p = lys[jj] * IW + lxs[ii];
            const float* bb = borderBuf + ((size_t)g * (IW * IW) + p) * NC_;
#pragma unroll
            for (int q = 0; q < NC_; ++q) acc[q] += bb[q];
        }
    float* ob = out + (size_t)b * NC_ * S_ * S_ + gy * S_ + gx;
#pragma unroll
    for (int q = 0; q < NC_; ++q) ob[(size_t)q * S_ * S_] = acc[q];
}

// ---- fallback: direct atomic scatter (any shape) ----
__global__ void __launch_bounds__(256)
scatter_cic_kernel(const float* __restrict__ points,
                   const float* __restrict__ values,
                   float* __restrict__ out, int N) {
    const int n = blockIdx.x * blockDim.x + threadIdx.x;
    const int b = blockIdx.y;
    if (n >= N) return;
    const float* pb = points + (size_t)b * 2 * N;
    const float px = (pb[n] + 0.5f) * (float)S_;
    const float py = (pb[(size_t)N + n] + 0.5f) * (float)S_;
    const float xf = floorf(px), yf = floorf(py);
    const float rx = px - xf, ry = py - yf;
    const int xi = (int)xf, yi = (int)yf;
    const float* vb = values + (size_t)b * NC_ * N + n;
    float v[NC_];
#pragma unroll
    for (int c = 0; c < NC_; ++c) v[c] = vb[(size_t)c * N];
    float* ob = out + (size_t)b * NC_ * S_ * S_;
#pragma unroll
    for (int dx = 0; dx < 2; ++dx) {
        const int x_ = xi + dx;
        if (x_ < 0 || x_ >= S_) continue;
        const float wx = dx ? rx : (1.0f - rx);
#pragma unroll
        for (int dy = 0; dy < 2; ++dy) {
            const int y_ = yi + dy;
            if (y_ < 0 || y_ >= S_) continue;
            const float w = wx * (dy ? ry : (1.0f - ry));
            const int idx = y_ * S_ + x_;
#pragma unroll
            for (int c = 0; c < NC_; ++c)
                atomicAdd(ob + (size_t)c * S_ * S_ + idx, w * v[c]);
        }
    }
}

extern "C" void kernel_launch(void* const* d_in, const int* in_sizes, int n_in,
                              void* d_out, int out_size, void* d_ws, size_t ws_size,
                              hipStream_t stream) {
    const float* points = (const float*)d_in[0];   // [B, 2, N]
    const float* values = (const float*)d_in[1];   // [B, NC, N]
    float* out = (float*)d_out;                    // [B, NC, S, S]

    const int B = out_size / (NC_ * S_ * S_);      // 16
    const int N = in_sizes[0] / (2 * B);           // 262144

    const size_t P = (size_t)B * N;
    const int cpb = N / CHUNK;                     // 256
    const int chunksTotal = B * cpb;               // 4096
    const int nSlab = B * NBIN2;                   // 1024 tiles

    const size_t recBytes    = (size_t)nSlab * CAPR * 24;    // 113.2 MB slabs
    const size_t borderElems = (size_t)nSlab * (IW * IW) * NC_;
    const size_t ovfBytes    = P * 7 * 4;          // worst-case overflow list
    const size_t wsNeeded    = recBytes + (size_t)(nSlab + 1) * 4 +
                               borderElems * 4 + ovfBytes + 256;

    const bool fast = (N % CHUNK == 0) && (N >= CHUNK) && (B > 0) &&
                      (P < (1u << 31) / 2) && (ws_size >= wsNeeded);

    if (fast) {
        char* w = (char*)d_ws;
        uint2* recsA     = (uint2*)w;
        u32* cursor      = (u32*)(w + recBytes);   // nSlab counters
        u32* ovfCnt      = cursor + nSlab;         // +1 overflow counter
        float* borderBuf = (float*)(ovfCnt + 1);
        u32* ovfBuf      = (u32*)(borderBuf + borderElems);

        hipMemsetAsync(cursor, 0, (size_t)(nSlab + 1) * 4, stream);
        k_scatter<<<chunksTotal, 256, 0, stream>>>(points, values, cursor,
                                                   ovfCnt, ovfBuf, recsA, N);
        k_fused<<<nSlab, 256, 0, stream>>>(recsA, cursor, out, borderBuf);
        const int borderTotal = B * 4032;
        k_border<<<(borderTotal + 255) / 256 + CLEAN_T / 256, 256, 0, stream>>>(
            borderBuf, out, ovfCnt, ovfBuf, borderTotal);
        // every output pixel is written by k_fused (interior) or k_border
    } else {
        hipMemsetAsync(d_out, 0, (size_t)out_size * sizeof(float), stream);
        dim3 block(256, 1, 1);
        dim3 grid((N + 255) / 256, B, 1);
        scatter_cic_kernel<<<grid, block, 0, stream>>>(points, values, out, N);
    }
}

// Round 5
// 352.384 us; speedup vs baseline: 3.2213x; 3.2213x over previous
//
#include <hip/hip_runtime.h>

// Problem constants: BOX=256, OS=1 -> S=256, NC=10, B=16, N=262144
#define S_     256
#define NC_    10
#define CHUNK  1024         // points per staging block
#define TS     32           // scatter tile size (32x32 px)
#define NBIN2  64           // 8x8 tiles of 32px per batch
#define CAPR   4608         // record slab per tile (mean 4096, +8 sigma)
#define IW     33           // LDS image width (32+1 for dx/dy=1 spill)
#define IMSZ   (NC_ * IW * IW)   // 10890 words = 43.6 KB
#define FPSCALE 262144.0f        // 2^18 fixed-point scale for LDS s32 accum
#define FPINV   (1.0f / 262144.0f)

typedef unsigned int u32;

__device__ __forceinline__ u32 f2bf(float f) {          // f32 -> bf16 (RNE)
    u32 u = __float_as_uint(f);
    return (u + 0x7fffu + ((u >> 16) & 1u)) >> 16;
}
__device__ __forceinline__ float bf2f(u32 h) { return __uint_as_float(h << 16); }

// Record (24 B, 3x uint2): w0 = qx | qy<<16 (tile-local coords, fp 1/2048 px,
// 16-bit fields: 5-bit cell + 11-bit fraction); w1..w5 = 10 bf16 values.
//
// R5 pipeline: memset(cursor) -> k_scatter (64 coarse bins, coalesced runs)
// -> k_fused (LDS-image deposit with NATIVE u32 ds_add — R4 lesson: f32
// atomicAdd on LDS compiles to a ~200cy CAS loop, 855us; s32 fixed-point
// at 2^18 is a single ds_add_u32) -> k_border (border + overflow tail).

// ---- K3: in-LDS counting sort per chunk, then coalesced record flush ----
__global__ void __launch_bounds__(256)
k_scatter(const float* __restrict__ points, const float* __restrict__ values,
          u32* __restrict__ cursor, u32* __restrict__ ovfCnt,
          u32* __restrict__ ovfBuf, uint2* __restrict__ recs, int N) {
    __shared__ u32 cnt[NBIN2];          // histogram -> LDS sort cursor
    __shared__ u32 gOff[NBIN2];         // global slab base - excl
    __shared__ unsigned char binId[CHUNK];
    __shared__ u32 lw[6][CHUNK];        // 24 KB sorted record words (SoA)

    const int tid = threadIdx.x;
    const int cpb = N / CHUNK;
    const int b  = blockIdx.x / cpb;
    const int n0 = (blockIdx.x % cpb) * CHUNK;
    const float* pb = points + (size_t)b * 2 * N;
    const float* vb = values + (size_t)b * NC_ * N;
    const int nb = n0 + tid * 4;

    if (tid < NBIN2) cnt[tid] = 0;

    const float4 pxv = *(const float4*)(pb + nb);
    const float4 pyv = *(const float4*)(pb + (size_t)N + nb);
    float4 vv[NC_];
#pragma unroll
    for (int c = 0; c < NC_; ++c)
        vv[c] = *(const float4*)(vb + (size_t)c * N + nb);

    __syncthreads();                     // cnt zeroed

    // phase 1: quantize 4 points, per-block 64-bin histogram
    float px4[4] = {pxv.x, pxv.y, pxv.z, pxv.w};
    float py4[4] = {pyv.x, pyv.y, pyv.z, pyv.w};
    u32 w0[4], binA[4];
#pragma unroll
    for (int k = 0; k < 4; ++k) {
        float px = (px4[k] + 0.5f) * (float)S_;
        float py = (py4[k] + 0.5f) * (float)S_;
        int xi = (int)floorf(px), yi = (int)floorf(py);
        u32 qx = __float2uint_rn((px - (float)(xi & ~31)) * 2048.0f);
        u32 qy = __float2uint_rn((py - (float)(yi & ~31)) * 2048.0f);
        qx = min(qx, 65535u); qy = min(qy, 65535u);
        w0[k] = qx | (qy << 16);
        binA[k] = (u32)(((yi >> 5) << 3) + (xi >> 5));
        atomicAdd(&cnt[binA[k]], 1u);
    }
    __syncthreads();

    // phase 2: wave-0 shfl exclusive scan of 64 bins + global slab claim
    if (tid < NBIN2) {
        u32 myCnt = cnt[tid];
        u32 x = myCnt;
#pragma unroll
        for (int off = 1; off < 64; off <<= 1) {
            u32 y = __shfl_up(x, off, 64);
            if (tid >= off) x += y;
        }
        u32 excl = x - myCnt;
        u32 gt = (u32)b * NBIN2 + (u32)tid;
        u32 gbase = 0;
        if (myCnt) gbase = gt * (u32)CAPR + atomicAdd(&cursor[gt], myCnt);
        gOff[tid] = gbase - excl;
        cnt[tid] = excl;                 // becomes LDS sort cursor
    }
    __syncthreads();

    // phase 3: pack records, scatter into LDS in bin order
#pragma unroll
    for (int k = 0; k < 4; ++k) {
        u32 bin = binA[k];
        u32 slot = atomicAdd(&cnt[bin], 1u);
        binId[slot] = (unsigned char)bin;
#define VG(c) ((&vv[c].x)[k])
        lw[0][slot] = w0[k];
        lw[1][slot] = f2bf(VG(0)) | (f2bf(VG(1)) << 16);
        lw[2][slot] = f2bf(VG(2)) | (f2bf(VG(3)) << 16);
        lw[3][slot] = f2bf(VG(4)) | (f2bf(VG(5)) << 16);
        lw[4][slot] = f2bf(VG(6)) | (f2bf(VG(7)) << 16);
        lw[5][slot] = f2bf(VG(8)) | (f2bf(VG(9)) << 16);
#undef VG
    }
    __syncthreads();

    // phase 4: coalesced flush; runs avg 16 records (384 B contiguous)
    const u32 tb0 = (u32)b * NBIN2;
#pragma unroll
    for (int k = 0; k < 4; ++k) {
        u32 r = (u32)tid + (u32)k * 256;
        u32 bin = binId[r];
        u32 dst = gOff[bin] + r;
        u32 a0 = lw[0][r], a1 = lw[1][r], a2 = lw[2][r],
            a3 = lw[3][r], a4 = lw[4][r], a5 = lw[5][r];
        u32 rel = dst - (tb0 + bin) * (u32)CAPR;
        if (rel < (u32)CAPR) {           // always true unless tile > CAPR recs
            size_t s3 = (size_t)dst * 3;
            recs[s3]     = make_uint2(a0, a1);
            recs[s3 + 1] = make_uint2(a2, a3);
            recs[s3 + 2] = make_uint2(a4, a5);
        } else {                         // slab overflow -> side list
            u32 oi = atomicAdd(ovfCnt, 1u);
            u32* ob = ovfBuf + (size_t)oi * 7;
            ob[0] = tb0 + bin;
            ob[1] = a0; ob[2] = a1; ob[3] = a2;
            ob[4] = a3; ob[5] = a4; ob[6] = a5;
        }
    }
}

// ---- K4: LDS-image fixed-point deposit, one block per 32x32 tile ----
// Streams the tile's records and accumulates w*v*2^18 into a 33x33x10 s32
// LDS image with native ds_add_u32 (fire-and-forget, throughput-bound).
// Interior 31x31 pixels -> plain global stores; border ring -> borderBuf.
__global__ void __launch_bounds__(256)
k_fused(const uint2* __restrict__ recs, const u32* __restrict__ cursor,
        float* __restrict__ out, float* __restrict__ borderBuf) {
    __shared__ u32 img[IMSZ];           // 43.6 KB -> 3 blocks/CU

    const int tid = threadIdx.x;
    const int g = blockIdx.x;                       // batch*64 + tile
    const int batch = g >> 6, t = g & 63;
    const int ox = (t & 7) * TS, oy = (t >> 3) * TS;
    const u32 base = (u32)g * (u32)CAPR;            // fixed slab base
    const u32 n = min(cursor[g], (u32)CAPR);        // overflow -> k_border tail

    for (int p = tid; p < IMSZ; p += 256) img[p] = 0u;
    __syncthreads();

    for (u32 i = tid; i < n; i += 256) {
        size_t sa = (size_t)(base + i) * 3;
        uint2 a = recs[sa], b2 = recs[sa + 1], c2 = recs[sa + 2];
        u32 qx = a.x & 0xffffu, qy = a.x >> 16;
        int xi = (int)(qx >> 11), yi = (int)(qy >> 11);
        float rx = (float)(qx & 2047u) * (1.0f / 2048.0f);
        float ry = (float)(qy & 2047u) * (1.0f / 2048.0f);
        float w00 = (1.0f - rx) * (1.0f - ry) * FPSCALE;   // (xi,   yi  )
        float w10 = rx * (1.0f - ry) * FPSCALE;            // (xi+1, yi  )
        float w01 = (1.0f - rx) * ry * FPSCALE;            // (xi,   yi+1)
        float w11 = rx * ry * FPSCALE;                     // (xi+1, yi+1)
        int p00 = yi * IW + xi;
        float v[NC_];
        v[0] = bf2f(a.y & 0xffffu);  v[1] = bf2f(a.y >> 16);
        v[2] = bf2f(b2.x & 0xffffu); v[3] = bf2f(b2.x >> 16);
        v[4] = bf2f(b2.y & 0xffffu); v[5] = bf2f(b2.y >> 16);
        v[6] = bf2f(c2.x & 0xffffu); v[7] = bf2f(c2.x >> 16);
        v[8] = bf2f(c2.y & 0xffffu); v[9] = bf2f(c2.y >> 16);
#pragma unroll
        for (int c = 0; c < NC_; ++c) {
            float vc = v[c];
            u32* ib = img + c * (IW * IW) + p00;  // c*IW*IW*4 = imm offset
            atomicAdd(ib,          (u32)__float2int_rn(w00 * vc));
            atomicAdd(ib + 1,      (u32)__float2int_rn(w10 * vc));
            atomicAdd(ib + IW,     (u32)__float2int_rn(w01 * vc));
            atomicAdd(ib + IW + 1, (u32)__float2int_rn(w11 * vc));
        }
    }
    __syncthreads();

    // writeback: interior (lx,ly in 1..31) owned uniquely by this tile
    for (int p = tid; p < IW * IW; p += 256) {
        int lx = p % IW, ly = p / IW;
        bool interior = (lx >= 1) & (lx <= 31) & (ly >= 1) & (ly <= 31);
        if (interior) {
            int gx = ox + lx, gy = oy + ly;
            float* ob = out + (size_t)batch * NC_ * S_ * S_ + gy * S_ + gx;
#pragma unroll
            for (int q = 0; q < NC_; ++q)
                ob[(size_t)q * S_ * S_] =
                    (float)(int)img[q * (IW * IW) + p] * FPINV;
        } else {
            float* bb = borderBuf + ((size_t)g * (IW * IW) + p) * NC_;
#pragma unroll
            for (int q = 0; q < NC_; ++q)
                bb[q] = (float)(int)img[q * (IW * IW) + p] * FPINV;
        }
    }
}

// ---- K5: combine border partials; tail blocks process slab-overflow list ----
// Border px per batch: 8 cols x 256 + 8 rows x 248 = 4032.
#define CLEAN_T 4096                                 // 16 tail blocks
__global__ void __launch_bounds__(256)
k_border(const float* __restrict__ borderBuf, float* __restrict__ out,
         const u32* __restrict__ ovfCnt, const u32* __restrict__ ovfBuf,
         int total) {
    int idx = blockIdx.x * 256 + threadIdx.x;
    if (idx >= total) {
        // overflow-cleanup role (no-op unless a tile exceeded CAPR records)
        u32 oc = *ovfCnt;
        for (u32 j = (u32)(idx - total); j < oc; j += CLEAN_T) {
            const u32* ob = ovfBuf + (size_t)j * 7;
            u32 g = ob[0];
            int batch = (int)(g >> 6), t = (int)(g & 63u);
            int ox = (t & 7) * TS, oy = (t >> 3) * TS;
            u32 w0 = ob[1];
            u32 qx = w0 & 0xffffu, qy = w0 >> 16;
            int xi = ox + (int)(qx >> 11), yi = oy + (int)(qy >> 11);
            float rx = (float)(qx & 2047u) * (1.0f / 2048.0f);
            float ry = (float)(qy & 2047u) * (1.0f / 2048.0f);
            float v[NC_];
            v[0] = bf2f(ob[2] & 0xffffu); v[1] = bf2f(ob[2] >> 16);
            v[2] = bf2f(ob[3] & 0xffffu); v[3] = bf2f(ob[3] >> 16);
            v[4] = bf2f(ob[4] & 0xffffu); v[5] = bf2f(ob[4] >> 16);
            v[6] = bf2f(ob[5] & 0xffffu); v[7] = bf2f(ob[5] >> 16);
            v[8] = bf2f(ob[6] & 0xffffu); v[9] = bf2f(ob[6] >> 16);
            float* obase = out + (size_t)batch * NC_ * S_ * S_;
            for (int dx = 0; dx < 2; ++dx) {
                int x_ = xi + dx; if (x_ >= S_) continue;
                float wx = dx ? rx : (1.0f - rx);
                for (int dy = 0; dy < 2; ++dy) {
                    int y_ = yi + dy; if (y_ >= S_) continue;
                    float w = wx * (dy ? ry : (1.0f - ry));
                    for (int cc = 0; cc < NC_; ++cc)
                        atomicAdd(obase + (size_t)cc * S_ * S_ + y_ * S_ + x_,
                                  w * v[cc]);
                }
            }
        }
        return;
    }
    int b = idx / 4032;
    int j = idx - b * 4032;
    int gx, gy;
    if (j < 2048) {                                  // vertical lines gx%32==0
        gx = (j >> 8) << 5;
        gy = j & 255;
    } else {                                         // horizontal, gx%32!=0
        int j2 = j - 2048;
        int row = j2 / 248, col = j2 - row * 248;
        gy = row << 5;
        gx = col + 1 + col / 31;                     // 0..247 -> 1..255 \ {32k}
    }

    int txs[2], lxs[2], nx = 0;
    bool bx = (gx & 31) == 0, by = (gy & 31) == 0;
    if (bx) {
        if (gx > 0) { txs[nx] = (gx >> 5) - 1; lxs[nx] = 32; ++nx; }
        txs[nx] = gx >> 5; lxs[nx] = 0; ++nx;
    } else { txs[0] = gx >> 5; lxs[0] = gx & 31; nx = 1; }
    int tys[2], lys[2], ny = 0;
    if (by) {
        if (gy > 0) { tys[ny] = (gy >> 5) - 1; lys[ny] = 32; ++ny; }
        tys[ny] = gy >> 5; lys[ny] = 0; ++ny;
    } else { tys[0] = gy >> 5; lys[0] = gy & 31; ny = 1; }

    float acc[NC_];
#pragma unroll
    for (int q = 0; q < NC_; ++q) acc[q] = 0.0f;
    for (int jj = 0; jj < ny; ++jj)
        for (int ii = 0; ii < nx; ++ii) {
            int g = (b << 6) + (tys[jj] << 3) + txs[ii];
            int p = lys[jj] * IW + lxs[ii];
            const float* bb = borderBuf + ((size_t)g * (IW * IW) + p) * NC_;
#pragma unroll
            for (int q = 0; q < NC_; ++q) acc[q] += bb[q];
        }
    float* ob = out + (size_t)b * NC_ * S_ * S_ + gy * S_ + gx;
#pragma unroll
    for (int q = 0; q < NC_; ++q) ob[(size_t)q * S_ * S_] = acc[q];
}

// ---- fallback: direct atomic scatter (any shape) ----
__global__ void __launch_bounds__(256)
scatter_cic_kernel(const float* __restrict__ points,
                   const float* __restrict__ values,
                   float* __restrict__ out, int N) {
    const int n = blockIdx.x * blockDim.x + threadIdx.x;
    const int b = blockIdx.y;
    if (n >= N) return;
    const float* pb = points + (size_t)b * 2 * N;
    const float px = (pb[n] + 0.5f) * (float)S_;
    const float py = (pb[(size_t)N + n] + 0.5f) * (float)S_;
    const float xf = floorf(px), yf = floorf(py);
    const float rx = px - xf, ry = py - yf;
    const int xi = (int)xf, yi = (int)yf;
    const float* vb = values + (size_t)b * NC_ * N + n;
    float v[NC_];
#pragma unroll
    for (int c = 0; c < NC_; ++c) v[c] = vb[(size_t)c * N];
    float* ob = out + (size_t)b * NC_ * S_ * S_;
#pragma unroll
    for (int dx = 0; dx < 2; ++dx) {
        const int x_ = xi + dx;
        if (x_ < 0 || x_ >= S_) continue;
        const float wx = dx ? rx : (1.0f - rx);
#pragma unroll
        for (int dy = 0; dy < 2; ++dy) {
            const int y_ = yi + dy;
            if (y_ < 0 || y_ >= S_) continue;
            const float w = wx * (dy ? ry : (1.0f - ry));
            const int idx = y_ * S_ + x_;
#pragma unroll
            for (int c = 0; c < NC_; ++c)
                atomicAdd(ob + (size_t)c * S_ * S_ + idx, w * v[c]);
        }
    }
}

extern "C" void kernel_launch(void* const* d_in, const int* in_sizes, int n_in,
                              void* d_out, int out_size, void* d_ws, size_t ws_size,
                              hipStream_t stream) {
    const float* points = (const float*)d_in[0];   // [B, 2, N]
    const float* values = (const float*)d_in[1];   // [B, NC, N]
    float* out = (float*)d_out;                    // [B, NC, S, S]

    const int B = out_size / (NC_ * S_ * S_);      // 16
    const int N = in_sizes[0] / (2 * B);           // 262144

    const size_t P = (size_t)B * N;
    const int cpb = N / CHUNK;                     // 256
    const int chunksTotal = B * cpb;               // 4096
    const int nSlab = B * NBIN2;                   // 1024 tiles

    const size_t recBytes    = (size_t)nSlab * CAPR * 24;    // 113.2 MB slabs
    const size_t borderElems = (size_t)nSlab * (IW * IW) * NC_;
    const size_t ovfBytes    = P * 7 * 4;          // worst-case overflow list
    const size_t wsNeeded    = recBytes + (size_t)(nSlab + 1) * 4 +
                               borderElems * 4 + ovfBytes + 256;

    const bool fast = (N % CHUNK == 0) && (N >= CHUNK) && (B > 0) &&
                      (P < (1u << 31) / 2) && (ws_size >= wsNeeded);

    if (fast) {
        char* w = (char*)d_ws;
        uint2* recsA     = (uint2*)w;
        u32* cursor      = (u32*)(w + recBytes);   // nSlab counters
        u32* ovfCnt      = cursor + nSlab;         // +1 overflow counter
        float* borderBuf = (float*)(ovfCnt + 1);
        u32* ovfBuf      = (u32*)(borderBuf + borderElems);

        hipMemsetAsync(cursor, 0, (size_t)(nSlab + 1) * 4, stream);
        k_scatter<<<chunksTotal, 256, 0, stream>>>(points, values, cursor,
                                                   ovfCnt, ovfBuf, recsA, N);
        k_fused<<<nSlab, 256, 0, stream>>>(recsA, cursor, out, borderBuf);
        const int borderTotal = B * 4032;
        k_border<<<(borderTotal + 255) / 256 + CLEAN_T / 256, 256, 0, stream>>>(
            borderBuf, out, ovfCnt, ovfBuf, borderTotal);
        // every output pixel is written by k_fused (interior) or k_border
    } else {
        hipMemsetAsync(d_out, 0, (size_t)out_size * sizeof(float), stream);
        dim3 block(256, 1, 1);
        dim3 grid((N + 255) / 256, B, 1);
        scatter_cic_kernel<<<grid, block, 0, stream>>>(points, values, out, N);
    }
}

// Round 6
// 347.607 us; speedup vs baseline: 3.2655x; 1.0137x over previous
//
#include <hip/hip_runtime.h>

// Problem constants: BOX=256, OS=1 -> S=256, NC=10, B=16, N=262144
#define S_     256
#define NC_    10
#define CHUNK  1024         // points per processed chunk (2 chunks per block)
#define TS     32           // scatter tile size (32x32 px)
#define NBIN2  64           // 8x8 tiles of 32px per batch
#define CAPR   4608         // record slab per tile (mean 4096, +8 sigma)
#define IW     33           // LDS image width (32+1 for dx/dy=1 spill)
#define IMSZ   (NC_ * IW * IW)   // 10890 words = 43.6 KB
#define FPSCALE 262144.0f        // 2^18 fixed-point scale for LDS s32 accum
#define FPINV   (1.0f / 262144.0f)

typedef unsigned int u32;
typedef float f32x4 __attribute__((ext_vector_type(4)));

__device__ __forceinline__ u32 f2bf(float f) {          // f32 -> bf16 (RNE)
    u32 u = __float_as_uint(f);
    return (u + 0x7fffu + ((u >> 16) & 1u)) >> 16;
}
__device__ __forceinline__ float bf2f(u32 h) { return __uint_as_float(h << 16); }

// Inline-asm global load: issue point is pinned in program order (volatile),
// so the compiler cannot sink it to first use (R5 lesson: VGPR_Count=40
// proved hipcc sank the value loads into the consumption phase -> full
// latency exposed per wave). Waits are manual counted s_waitcnt.
#define GLOAD4(dst, addr) \
    asm volatile("global_load_dwordx4 %0, %1, off" : "=v"(dst) : "v"(addr))

// Record (24 B, 3x uint2): w0 = qx | qy<<16 (tile-local coords, fp 1/2048 px);
// w1..w5 = 10 bf16 values.
//
// R6 pipeline: memset(cursor) -> k_scatter (2 chunks/block, asm-issued loads,
// counted vmcnt waits: B's latency hides under ALL of A's processing)
// -> k_fused (u32 ds_add fixed-point LDS image) -> k_border.

// ---- K3: dual-chunk pipelined counting sort + coalesced record flush ----
__global__ void __launch_bounds__(256)
k_scatter(const float* __restrict__ points, const float* __restrict__ values,
          u32* __restrict__ cursor, u32* __restrict__ ovfCnt,
          u32* __restrict__ ovfBuf, uint2* __restrict__ recs, int N) {
    __shared__ u32 cnt[NBIN2];          // histogram -> LDS sort cursor
    __shared__ u32 gOff[NBIN2];         // global slab base - excl
    __shared__ unsigned char binId[CHUNK];
    __shared__ u32 lw[6][CHUNK];        // 24 KB sorted record words (SoA)

    const int tid = threadIdx.x;
    const int ppb = N / (2 * CHUNK);    // chunk-pairs per batch
    const int b  = blockIdx.x / ppb;
    const int n0 = (blockIdx.x % ppb) * (2 * CHUNK);
    const float* pb = points + (size_t)b * 2 * N;
    const float* vb = values + (size_t)b * NC_ * N;
    const int nA = n0 + tid * 4;
    const int nB = nA + CHUNK;

    // issue ALL 24 loads up front: 4 pos (oldest), 10 A-vals, 10 B-vals
    f32x4 pxA, pyA, pxB, pyB, vA[NC_], vB[NC_];
    GLOAD4(pxA, pb + nA);
    GLOAD4(pyA, pb + (size_t)N + nA);
    GLOAD4(pxB, pb + nB);
    GLOAD4(pyB, pb + (size_t)N + nB);
#pragma unroll
    for (int c = 0; c < NC_; ++c) GLOAD4(vA[c], vb + (size_t)c * N + nA);
#pragma unroll
    for (int c = 0; c < NC_; ++c) GLOAD4(vB[c], vb + (size_t)c * N + nB);

    if (tid < NBIN2) cnt[tid] = 0;
    __syncthreads();

    auto process = [&](const f32x4& pxv, const f32x4& pyv,
                       const f32x4 (&vv)[NC_], bool firstChunk) {
        // phase 1: quantize 4 points, per-chunk 64-bin histogram
        u32 w0[4], binA[4];
#pragma unroll
        for (int k = 0; k < 4; ++k) {
            float px = (pxv[k] + 0.5f) * (float)S_;
            float py = (pyv[k] + 0.5f) * (float)S_;
            int xi = (int)floorf(px), yi = (int)floorf(py);
            u32 qx = __float2uint_rn((px - (float)(xi & ~31)) * 2048.0f);
            u32 qy = __float2uint_rn((py - (float)(yi & ~31)) * 2048.0f);
            qx = min(qx, 65535u); qy = min(qy, 65535u);
            w0[k] = qx | (qy << 16);
            binA[k] = (u32)(((yi >> 5) << 3) + (xi >> 5));
            atomicAdd(&cnt[binA[k]], 1u);
        }
        __syncthreads();

        // phase 2: wave-0 shfl exclusive scan of 64 bins + global slab claim
        if (tid < NBIN2) {
            u32 myCnt = cnt[tid];
            u32 x = myCnt;
#pragma unroll
            for (int off = 1; off < 64; off <<= 1) {
                u32 y = __shfl_up(x, off, 64);
                if (tid >= off) x += y;
            }
            u32 excl = x - myCnt;
            u32 gt = (u32)b * NBIN2 + (u32)tid;
            u32 gbase = 0;
            if (myCnt) gbase = gt * (u32)CAPR + atomicAdd(&cursor[gt], myCnt);
            gOff[tid] = gbase - excl;
            cnt[tid] = excl;             // becomes LDS sort cursor
        }
        __syncthreads();

        // wait for this chunk's value loads (manual: asm loads are untracked).
        // A-vals done when <=10 outstanding (B's 10 still in flight).
        if (firstChunk) asm volatile("s_waitcnt vmcnt(10)");
        else            asm volatile("s_waitcnt vmcnt(0)");
        __builtin_amdgcn_sched_barrier(0);

        // phase 3: pack records, scatter into LDS in bin order
#pragma unroll
        for (int k = 0; k < 4; ++k) {
            u32 bin = binA[k];
            u32 slot = atomicAdd(&cnt[bin], 1u);
            binId[slot] = (unsigned char)bin;
            lw[0][slot] = w0[k];
            lw[1][slot] = f2bf(vv[0][k]) | (f2bf(vv[1][k]) << 16);
            lw[2][slot] = f2bf(vv[2][k]) | (f2bf(vv[3][k]) << 16);
            lw[3][slot] = f2bf(vv[4][k]) | (f2bf(vv[5][k]) << 16);
            lw[4][slot] = f2bf(vv[6][k]) | (f2bf(vv[7][k]) << 16);
            lw[5][slot] = f2bf(vv[8][k]) | (f2bf(vv[9][k]) << 16);
        }
        __syncthreads();

        // phase 4: coalesced flush; runs avg 16 records (384 B contiguous)
        const u32 tb0 = (u32)b * NBIN2;
#pragma unroll
        for (int k = 0; k < 4; ++k) {
            u32 r = (u32)tid + (u32)k * 256;
            u32 bin = binId[r];
            u32 dst = gOff[bin] + r;
            u32 a0 = lw[0][r], a1 = lw[1][r], a2 = lw[2][r],
                a3 = lw[3][r], a4 = lw[4][r], a5 = lw[5][r];
            u32 rel = dst - (tb0 + bin) * (u32)CAPR;
            if (rel < (u32)CAPR) {       // true unless tile > CAPR records
                size_t s3 = (size_t)dst * 3;
                recs[s3]     = make_uint2(a0, a1);
                recs[s3 + 1] = make_uint2(a2, a3);
                recs[s3 + 2] = make_uint2(a4, a5);
            } else {                     // slab overflow -> side list
                u32 oi = atomicAdd(ovfCnt, 1u);
                u32* ob = ovfBuf + (size_t)oi * 7;
                ob[0] = tb0 + bin;
                ob[1] = a0; ob[2] = a1; ob[3] = a2;
                ob[4] = a3; ob[5] = a4; ob[6] = a5;
            }
        }
    };

    // chunk A: positions ready when <=20 outstanding (pos are the oldest 4)
    asm volatile("s_waitcnt vmcnt(20)");
    __builtin_amdgcn_sched_barrier(0);
    process(pxA, pyA, vA, true);

    __syncthreads();                     // flush-A reads of lw/binId/gOff done
    if (tid < NBIN2) cnt[tid] = 0;
    __syncthreads();
    process(pxB, pyB, vB, false);        // B loads landed long ago
}

// ---- K4: LDS-image fixed-point deposit, one block per 32x32 tile ----
// Native ds_add_u32 (R4 lesson: f32 LDS atomicAdd = CAS loop, 8x slower).
// 2-deep register prefetch on the record stream.
__global__ void __launch_bounds__(256)
k_fused(const uint2* __restrict__ recs, const u32* __restrict__ cursor,
        float* __restrict__ out, float* __restrict__ borderBuf) {
    __shared__ u32 img[IMSZ];           // 43.6 KB -> 3 blocks/CU

    const int tid = threadIdx.x;
    const int g = blockIdx.x;                       // batch*64 + tile
    const int batch = g >> 6, t = g & 63;
    const int ox = (t & 7) * TS, oy = (t >> 3) * TS;
    const u32 base = (u32)g * (u32)CAPR;            // fixed slab base
    const u32 n = min(cursor[g], (u32)CAPR);        // overflow -> k_border tail

    for (int p = tid; p < IMSZ; p += 256) img[p] = 0u;
    __syncthreads();

    u32 i = tid;
    uint2 a0, a1, a2;
    if (i < n) {
        const uint2* rp = recs + (size_t)(base + i) * 3;
        a0 = rp[0]; a1 = rp[1]; a2 = rp[2];
    }
    while (i < n) {
        u32 j = i + 256;
        uint2 b0, b1, b2;
        if (j < n) {                     // prefetch next record
            const uint2* rp = recs + (size_t)(base + j) * 3;
            b0 = rp[0]; b1 = rp[1]; b2 = rp[2];
        }
        u32 qx = a0.x & 0xffffu, qy = a0.x >> 16;
        int xi = (int)(qx >> 11), yi = (int)(qy >> 11);
        float rx = (float)(qx & 2047u) * (1.0f / 2048.0f);
        float ry = (float)(qy & 2047u) * (1.0f / 2048.0f);
        float w00 = (1.0f - rx) * (1.0f - ry) * FPSCALE;   // (xi,   yi  )
        float w10 = rx * (1.0f - ry) * FPSCALE;            // (xi+1, yi  )
        float w01 = (1.0f - rx) * ry * FPSCALE;            // (xi,   yi+1)
        float w11 = rx * ry * FPSCALE;                     // (xi+1, yi+1)
        int p00 = yi * IW + xi;
        float v[NC_];
        v[0] = bf2f(a1.x & 0xffffu); v[1] = bf2f(a1.x >> 16);
        v[2] = bf2f(a1.y & 0xffffu); v[3] = bf2f(a1.y >> 16);
        v[4] = bf2f(a2.x & 0xffffu); v[5] = bf2f(a2.x >> 16);
        v[6] = bf2f(a2.y & 0xffffu); v[7] = bf2f(a2.y >> 16);
        // a0.y holds v[0],v[1]; a1 holds v[2..5]; a2 holds v[6..9] -- keep
        // the R5 packing: w1..w5 = lw[1..5]
        v[0] = bf2f(a0.y & 0xffffu); v[1] = bf2f(a0.y >> 16);
        v[2] = bf2f(a1.x & 0xffffu); v[3] = bf2f(a1.x >> 16);
        v[4] = bf2f(a1.y & 0xffffu); v[5] = bf2f(a1.y >> 16);
        v[6] = bf2f(a2.x & 0xffffu); v[7] = bf2f(a2.x >> 16);
        v[8] = bf2f(a2.y & 0xffffu); v[9] = bf2f(a2.y >> 16);
#pragma unroll
        for (int c = 0; c < NC_; ++c) {
            float vc = v[c];
            u32* ib = img + c * (IW * IW) + p00;  // c*IW*IW*4 = imm offset
            atomicAdd(ib,          (u32)__float2int_rn(w00 * vc));
            atomicAdd(ib + 1,      (u32)__float2int_rn(w10 * vc));
            atomicAdd(ib + IW,     (u32)__float2int_rn(w01 * vc));
            atomicAdd(ib + IW + 1, (u32)__float2int_rn(w11 * vc));
        }
        a0 = b0; a1 = b1; a2 = b2;
        i = j;
    }
    __syncthreads();

    // writeback: interior (lx,ly in 1..31) owned uniquely by this tile
    for (int p = tid; p < IW * IW; p += 256) {
        int lx = p % IW, ly = p / IW;
        bool interior = (lx >= 1) & (lx <= 31) & (ly >= 1) & (ly <= 31);
        if (interior) {
            int gx = ox + lx, gy = oy + ly;
            float* ob = out + (size_t)batch * NC_ * S_ * S_ + gy * S_ + gx;
#pragma unroll
            for (int q = 0; q < NC_; ++q)
                ob[(size_t)q * S_ * S_] =
                    (float)(int)img[q * (IW * IW) + p] * FPINV;
        } else {
            float* bb = borderBuf + ((size_t)g * (IW * IW) + p) * NC_;
#pragma unroll
            for (int q = 0; q < NC_; ++q)
                bb[q] = (float)(int)img[q * (IW * IW) + p] * FPINV;
        }
    }
}

// ---- K5: combine border partials; tail blocks process slab-overflow list ----
// Border px per batch: 8 cols x 256 + 8 rows x 248 = 4032.
#define CLEAN_T 4096                                 // 16 tail blocks
__global__ void __launch_bounds__(256)
k_border(const float* __restrict__ borderBuf, float* __restrict__ out,
         const u32* __restrict__ ovfCnt, const u32* __restrict__ ovfBuf,
         int total) {
    int idx = blockIdx.x * 256 + threadIdx.x;
    if (idx >= total) {
        // overflow-cleanup role (no-op unless a tile exceeded CAPR records)
        u32 oc = *ovfCnt;
        for (u32 j = (u32)(idx - total); j < oc; j += CLEAN_T) {
            const u32* ob = ovfBuf + (size_t)j * 7;
            u32 g = ob[0];
            int batch = (int)(g >> 6), t = (int)(g & 63u);
            int ox = (t & 7) * TS, oy = (t >> 3) * TS;
            u32 w0 = ob[1];
            u32 qx = w0 & 0xffffu, qy = w0 >> 16;
            int xi = ox + (int)(qx >> 11), yi = oy + (int)(qy >> 11);
            float rx = (float)(qx & 2047u) * (1.0f / 2048.0f);
            float ry = (float)(qy & 2047u) * (1.0f / 2048.0f);
            float v[NC_];
            v[0] = bf2f(ob[2] & 0xffffu); v[1] = bf2f(ob[2] >> 16);
            v[2] = bf2f(ob[3] & 0xffffu); v[3] = bf2f(ob[3] >> 16);
            v[4] = bf2f(ob[4] & 0xffffu); v[5] = bf2f(ob[4] >> 16);
            v[6] = bf2f(ob[5] & 0xffffu); v[7] = bf2f(ob[5] >> 16);
            v[8] = bf2f(ob[6] & 0xffffu); v[9] = bf2f(ob[6] >> 16);
            float* obase = out + (size_t)batch * NC_ * S_ * S_;
            for (int dx = 0; dx < 2; ++dx) {
                int x_ = xi + dx; if (x_ >= S_) continue;
                float wx = dx ? rx : (1.0f - rx);
                for (int dy = 0; dy < 2; ++dy) {
                    int y_ = yi + dy; if (y_ >= S_) continue;
                    float w = wx * (dy ? ry : (1.0f - ry));
                    for (int cc = 0; cc < NC_; ++cc)
                        atomicAdd(obase + (size_t)cc * S_ * S_ + y_ * S_ + x_,
                                  w * v[cc]);
                }
            }
        }
        return;
    }
    int b = idx / 4032;
    int j = idx - b * 4032;
    int gx, gy;
    if (j < 2048) {                                  // vertical lines gx%32==0
        gx = (j >> 8) << 5;
        gy = j & 255;
    } else {                                         // horizontal, gx%32!=0
        int j2 = j - 2048;
        int row = j2 / 248, col = j2 - row * 248;
        gy = row << 5;
        gx = col + 1 + col / 31;                     // 0..247 -> 1..255 \ {32k}
    }

    int txs[2], lxs[2], nx = 0;
    bool bx = (gx & 31) == 0, by = (gy & 31) == 0;
    if (bx) {
        if (gx > 0) { txs[nx] = (gx >> 5) - 1; lxs[nx] = 32; ++nx; }
        txs[nx] = gx >> 5; lxs[nx] = 0; ++nx;
    } else { txs[0] = gx >> 5; lxs[0] = gx & 31; nx = 1; }
    int tys[2], lys[2], ny = 0;
    if (by) {
        if (gy > 0) { tys[ny] = (gy >> 5) - 1; lys[ny] = 32; ++ny; }
        tys[ny] = gy >> 5; lys[ny] = 0; ++ny;
    } else { tys[0] = gy >> 5; lys[0] = gy & 31; ny = 1; }

    float acc[NC_];
#pragma unroll
    for (int q = 0; q < NC_; ++q) acc[q] = 0.0f;
    for (int jj = 0; jj < ny; ++jj)
        for (int ii = 0; ii < nx; ++ii) {
            int g = (b << 6) + (tys[jj] << 3) + txs[ii];
            int p = lys[jj] * IW + lxs[ii];
            const float* bb = borderBuf + ((size_t)g * (IW * IW) + p) * NC_;
#pragma unroll
            for (int q = 0; q < NC_; ++q) acc[q] += bb[q];
        }
    float* ob = out + (size_t)b * NC_ * S_ * S_ + gy * S_ + gx;
#pragma unroll
    for (int q = 0; q < NC_; ++q) ob[(size_t)q * S_ * S_] = acc[q];
}

// ---- fallback: direct atomic scatter (any shape) ----
__global__ void __launch_bounds__(256)
scatter_cic_kernel(const float* __restrict__ points,
                   const float* __restrict__ values,
                   float* __restrict__ out, int N) {
    const int n = blockIdx.x * blockDim.x + threadIdx.x;
    const int b = blockIdx.y;
    if (n >= N) return;
    const float* pb = points + (size_t)b * 2 * N;
    const float px = (pb[n] + 0.5f) * (float)S_;
    const float py = (pb[(size_t)N + n] + 0.5f) * (float)S_;
    const float xf = floorf(px), yf = floorf(py);
    const float rx = px - xf, ry = py - yf;
    const int xi = (int)xf, yi = (int)yf;
    const float* vb = values + (size_t)b * NC_ * N + n;
    float v[NC_];
#pragma unroll
    for (int c = 0; c < NC_; ++c) v[c] = vb[(size_t)c * N];
    float* ob = out + (size_t)b * NC_ * S_ * S_;
#pragma unroll
    for (int dx = 0; dx < 2; ++dx) {
        const int x_ = xi + dx;
        if (x_ < 0 || x_ >= S_) continue;
        const float wx = dx ? rx : (1.0f - rx);
#pragma unroll
        for (int dy = 0; dy < 2; ++dy) {
            const int y_ = yi + dy;
            if (y_ < 0 || y_ >= S_) continue;
            const float w = wx * (dy ? ry : (1.0f - ry));
            const int idx = y_ * S_ + x_;
#pragma unroll
            for (int c = 0; c < NC_; ++c)
                atomicAdd(ob + (size_t)c * S_ * S_ + idx, w * v[c]);
        }
    }
}

extern "C" void kernel_launch(void* const* d_in, const int* in_sizes, int n_in,
                              void* d_out, int out_size, void* d_ws, size_t ws_size,
                              hipStream_t stream) {
    const float* points = (const float*)d_in[0];   // [B, 2, N]
    const float* values = (const float*)d_in[1];   // [B, NC, N]
    float* out = (float*)d_out;                    // [B, NC, S, S]

    const int B = out_size / (NC_ * S_ * S_);      // 16
    const int N = in_sizes[0] / (2 * B);           // 262144

    const size_t P = (size_t)B * N;
    const int pairsTotal = B * (N / (2 * CHUNK)); // 2048 blocks
    const int nSlab = B * NBIN2;                   // 1024 tiles

    const size_t recBytes    = (size_t)nSlab * CAPR * 24;    // 113.2 MB slabs
    const size_t borderElems = (size_t)nSlab * (IW * IW) * NC_;
    const size_t ovfBytes    = P * 7 * 4;          // worst-case overflow list
    const size_t wsNeeded    = recBytes + (size_t)(nSlab + 1) * 4 +
                               borderElems * 4 + ovfBytes + 256;

    const bool fast = (N % (2 * CHUNK) == 0) && (N >= 2 * CHUNK) && (B > 0) &&
                      (P < (1u << 31) / 2) && (ws_size >= wsNeeded);

    if (fast) {
        char* w = (char*)d_ws;
        uint2* recsA     = (uint2*)w;
        u32* cursor      = (u32*)(w + recBytes);   // nSlab counters
        u32* ovfCnt      = cursor + nSlab;         // +1 overflow counter
        float* borderBuf = (float*)(ovfCnt + 1);
        u32* ovfBuf      = (u32*)(borderBuf + borderElems);

        hipMemsetAsync(cursor, 0, (size_t)(nSlab + 1) * 4, stream);
        k_scatter<<<pairsTotal, 256, 0, stream>>>(points, values, cursor,
                                                  ovfCnt, ovfBuf, recsA, N);
        k_fused<<<nSlab, 256, 0, stream>>>(recsA, cursor, out, borderBuf);
        const int borderTotal = B * 4032;
        k_border<<<(borderTotal + 255) / 256 + CLEAN_T / 256, 256, 0, stream>>>(
            borderBuf, out, ovfCnt, ovfBuf, borderTotal);
        // every output pixel is written by k_fused (interior) or k_border
    } else {
        hipMemsetAsync(d_out, 0, (size_t)out_size * sizeof(float), stream);
        dim3 block(256, 1, 1);
        dim3 grid((N + 255) / 256, B, 1);
        scatter_cic_kernel<<<grid, block, 0, stream>>>(points, values, out, N);
    }
}